// Round 2
// baseline (13559.927 us; speedup 1.0000x reference)
//
#include <hip/hip_runtime.h>
#include <math.h>

#define NHEAD 16
#define DMODEL 1024
#define BATCH 2
#define QSCALE 0.125f

// =====================================================================
// GEMM: C[M,N] = op(A) @ B (+ epilogue). Tile 128(M) x 64(N), BK=16,
// 256 threads, 8x4 per thread. fp32.
// AT=false: A is MxK row-major. AT=true: A is KxM row-major (r_kernel).
// MODE 0: +bias. MODE 1: (acc+bias)*QSCALE (q proj).
// MODE 2: acc+bias+R (post proj + residual).
// MODE 3: Wrel store: row m=(head*64+h), col n=r -> C[head][r][h].
// =====================================================================
template<int MODE, bool AT>
__global__ __launch_bounds__(256) void gemm_k(
    const float* __restrict__ A, const float* __restrict__ B,
    const float* __restrict__ bias, const float* __restrict__ R,
    float* __restrict__ C, int M, int N, int K, int nrel)
{
  __shared__ float As[16][132];
  __shared__ float Bs[16][68];
  const int tid = threadIdx.x;
  const int bm = blockIdx.x * 128;
  const int bn = blockIdx.y * 64;
  const int tx = tid & 15;
  const int ty = tid >> 4;
  float acc[8][4];
#pragma unroll
  for (int i = 0; i < 8; ++i)
#pragma unroll
    for (int j = 0; j < 4; ++j) acc[i][j] = 0.f;

  for (int k0 = 0; k0 < K; k0 += 16) {
    if (AT) {
      const int mm = (tid & 31) * 4;
      int kk = tid >> 5;
#pragma unroll
      for (int p = 0; p < 2; ++p, kk += 8) {
        const float4 va = *(const float4*)(A + (size_t)(k0 + kk) * M + bm + mm);
        As[kk][mm + 0] = va.x; As[kk][mm + 1] = va.y;
        As[kk][mm + 2] = va.z; As[kk][mm + 3] = va.w;
      }
    } else {
      const int kk4 = (tid & 3) * 4;
      const int mr = tid >> 2;
#pragma unroll
      for (int p = 0; p < 2; ++p) {
        const int m = mr + p * 64;
        const float4 va = *(const float4*)(A + (size_t)(bm + m) * K + k0 + kk4);
        As[kk4 + 0][m] = va.x; As[kk4 + 1][m] = va.y;
        As[kk4 + 2][m] = va.z; As[kk4 + 3][m] = va.w;
      }
    }
    {
      const int nn = tid & 63;
      int kk = tid >> 6;
#pragma unroll
      for (int p = 0; p < 4; ++p, kk += 4) {
        float bld = 0.f;
        if (bn + nn < N) bld = B[(size_t)(k0 + kk) * N + bn + nn];
        Bs[kk][nn] = bld;
      }
    }
    __syncthreads();
#pragma unroll
    for (int kk = 0; kk < 16; ++kk) {
      const float4 a0 = *(const float4*)&As[kk][ty * 8];
      const float4 a1 = *(const float4*)&As[kk][ty * 8 + 4];
      const float4 b0 = *(const float4*)&Bs[kk][tx * 4];
      const float av[8] = {a0.x, a0.y, a0.z, a0.w, a1.x, a1.y, a1.z, a1.w};
      const float bb[4] = {b0.x, b0.y, b0.z, b0.w};
#pragma unroll
      for (int i = 0; i < 8; ++i)
#pragma unroll
        for (int j = 0; j < 4; ++j)
          acc[i][j] = fmaf(av[i], bb[j], acc[i][j]);
    }
    __syncthreads();
  }
#pragma unroll
  for (int i = 0; i < 8; ++i) {
    const int m = bm + ty * 8 + i;
#pragma unroll
    for (int j = 0; j < 4; ++j) {
      const int n = bn + tx * 4 + j;
      if (n >= N) continue;
      float vv = acc[i][j];
      if (MODE == 0) vv += bias[n];
      else if (MODE == 1) vv = (vv + bias[n]) * QSCALE;
      else if (MODE == 2) vv = vv + bias[n] + R[(size_t)m * N + n];
      if (MODE == 3)
        C[((size_t)(m >> 6) * nrel + n) * 64 + (m & 63)] = vv;
      else
        C[(size_t)m * N + n] = vv;
    }
  }
}

// =====================================================================
// trig table: T[d][r] = (d<512 ? sgn*sin : cos)((rmin+r*rstep)*invfreq(d&511))
// Derived from phi/pi/psi/omega products via angle addition.
// =====================================================================
__global__ void trig_fill(float* __restrict__ T, int nrel, int rmin,
                          int rstep, float sgn)
{
  const int r = blockIdx.x * 256 + threadIdx.x;
  const int d = blockIdx.y;
  if (r >= nrel) return;
  const int f = d & 511;
  const float invf = expf((float)f * -(9.210340371976184f / 512.0f));
  const float ang = (float)(rmin + r * rstep) * invf;
  float s, c;
  sincosf(ang, &s, &c);
  T[(size_t)d * nrel + r] = (d < 512) ? sgn * s : c;
}

// =====================================================================
// upsample: out[b][2t]=h[b][t]; out[b][2t+1]=0.5*(h[b][t]+h[b][(t-1)%L])
// NOTE: in the reference this runs at BLOCK ENTRY (before the block's
// self-layers), not immediately before the up-layer that consumes it.
// =====================================================================
__global__ void upsample_k(const float* __restrict__ h, float* __restrict__ out,
                           int L)
{
  const size_t idx = (size_t)blockIdx.x * 256 + threadIdx.x;
  const size_t total = (size_t)BATCH * 2 * L * DMODEL;
  if (idx >= total) return;
  const int d = (int)(idx & 1023);
  const int t2 = (int)((idx >> 10) % (size_t)(2 * L));
  const int b = (int)((idx >> 10) / (size_t)(2 * L));
  const float* hb = h + (size_t)b * L * DMODEL;
  float val;
  if ((t2 & 1) == 0) {
    val = hb[(size_t)(t2 >> 1) * DMODEL + d];
  } else {
    const int t = (t2 - 1) >> 1;
    const int prev = (t == 0) ? (L - 1) : (t - 1);
    val = 0.5f * (hb[(size_t)t * DMODEL + d] + hb[(size_t)prev * DMODEL + d]);
  }
  out[idx] = val;
}

// =====================================================================
// LayerNorm over D=1024; one block (256 thr) per row, 4 elems/thread.
// =====================================================================
__global__ __launch_bounds__(256) void ln_k(
    const float* __restrict__ x, const float* __restrict__ g,
    const float* __restrict__ b, float* __restrict__ out)
{
  const int row = blockIdx.x;
  const int tid = threadIdx.x;
  const float* xr = x + (size_t)row * DMODEL;
  const float4 xv = *(const float4*)(xr + tid * 4);
  __shared__ float red[4];
  float s = xv.x + xv.y + xv.z + xv.w;
#pragma unroll
  for (int off = 32; off > 0; off >>= 1) s += __shfl_down(s, off, 64);
  if ((tid & 63) == 0) red[tid >> 6] = s;
  __syncthreads();
  const float mean = (red[0] + red[1] + red[2] + red[3]) * (1.f / 1024.f);
  const float dx = xv.x - mean, dy = xv.y - mean;
  const float dz = xv.z - mean, dw = xv.w - mean;
  float vs = dx * dx + dy * dy + dz * dz + dw * dw;
  __syncthreads();
#pragma unroll
  for (int off = 32; off > 0; off >>= 1) vs += __shfl_down(vs, off, 64);
  if ((tid & 63) == 0) red[tid >> 6] = vs;
  __syncthreads();
  const float var = (red[0] + red[1] + red[2] + red[3]) * (1.f / 1024.f);
  const float rstd = rsqrtf(var + 1e-9f);
  const float4 gv = *(const float4*)(g + tid * 4);
  const float4 bv = *(const float4*)(b + tid * 4);
  float4 ov;
  ov.x = dx * rstd * gv.x + bv.x;
  ov.y = dy * rstd * gv.y + bv.y;
  ov.z = dz * rstd * gv.z + bv.z;
  ov.w = dw * rstd * gv.w + bv.w;
  *(float4*)(out + (size_t)row * DMODEL + tid * 4) = ov;
}

// =====================================================================
// Flash attention with relative-position band + token-type term.
// Block = 256 threads, 32 queries/block, key tiles of TK (64 or 32).
// score[i][j] = dot(q+rw*s, k_j) + dot(q+rr*s, Wrel[n][ri(i,j)]) + tok
// ri = sqp*i - skp*j + rbase (index into per-layer Wrel of length nrel).
// Online softmax; o accumulated in registers (8 h per thread).
// =====================================================================
template<int TK>
__global__ __launch_bounds__(256) void attn_k(
    const float* __restrict__ q, const float* __restrict__ k,
    const float* __restrict__ v, const float* __restrict__ wrel,
    const float* __restrict__ rw, const float* __restrict__ rr,
    const float* __restrict__ rs, const float* __restrict__ seg,
    const int* __restrict__ ids, float* __restrict__ vec,
    int Lq, int Lk, int sq, int sk, int sqp, int skp, int rbase, int nrel)
{
  constexpr int JPT = TK / 16;   // j per thread in score phase
  constexpr int CPL = TK / 8;    // cols per lane in softmax phase
  __shared__ float qwS[32][68];
  __shared__ float q2S[32][68];
  __shared__ float kvS[64][68];
  __shared__ float bandS[95][68];
  __shared__ float PS[32][65];
  __shared__ float mrow[32], lrow[32], arow[32], tb0[32], tb1[32];
  __shared__ int idqS[32], idkS[64];

  const int tid = threadIdx.x;
  const int b = blockIdx.z;
  const int n = blockIdx.y;
  const int i0 = blockIdx.x * 32;
  const float* qb = q + ((size_t)b * Lq + i0) * DMODEL + n * 64;

  for (int e = tid; e < 32 * 64; e += 256) {
    const int i = e >> 6, h = e & 63;
    const float qv = qb[(size_t)i * DMODEL + h];
    qwS[i][h] = qv + rw[n * 64 + h] * QSCALE;
    q2S[i][h] = qv + rr[n * 64 + h] * QSCALE;
  }
  if (tid < 64) {
    const int i = tid >> 1, s_ = tid & 1;
    float a = 0.f;
    for (int h = 0; h < 64; ++h)
      a += (qb[(size_t)i * DMODEL + h] + rs[n * 64 + h] * QSCALE) *
           seg[(s_ * NHEAD + n) * 64 + h];
    if (s_) tb1[i] = a; else tb0[i] = a;
  }
  if (tid < 32) {
    mrow[tid] = -1e30f;
    lrow[tid] = 0.f;
    idqS[tid] = ids[b * 1024 + sq * (i0 + tid)];
  }
  float o[8];
#pragma unroll
  for (int x = 0; x < 8; ++x) o[x] = 0.f;
  const int tx = tid & 15, ty = tid >> 4;
  const int ip = tid >> 3, hp = (tid & 7) * 8;
  const int W = sqp * 31 + skp * (TK - 1) + 1;  // band rows, <= 95

  for (int jt = 0; jt < Lk; jt += TK) {
    __syncthreads();
    const float* kb = k + ((size_t)b * Lk + jt) * DMODEL + n * 64;
    for (int e = tid; e < TK * 64; e += 256) {
      const int j = e >> 6, h = e & 63;
      kvS[j][h] = kb[(size_t)j * DMODEL + h];
    }
    if (tid < TK) idkS[tid] = ids[b * 1024 + sk * (jt + tid)];
    const int rlo = sqp * i0 - skp * (jt + TK - 1) + rbase;
    const float* wb = wrel + ((size_t)n * nrel + rlo) * 64;
    for (int e = tid; e < W * 64; e += 256) {
      const int r = e >> 6, h = e & 63;
      bandS[r][h] = wb[(size_t)r * 64 + h];
    }
    __syncthreads();

    float sc[2][JPT];
    int ril[2][JPT];
#pragma unroll
    for (int ii = 0; ii < 2; ++ii)
#pragma unroll
      for (int jj = 0; jj < JPT; ++jj) {
        sc[ii][jj] = 0.f;
        ril[ii][jj] = sqp * (i0 + ty * 2 + ii) - skp * (jt + tx + jj * 16)
                      + rbase - rlo;
      }
#pragma unroll 4
    for (int h4 = 0; h4 < 16; ++h4) {
      const float4 aw0 = *(const float4*)&qwS[ty * 2][h4 * 4];
      const float4 aw1 = *(const float4*)&qwS[ty * 2 + 1][h4 * 4];
      const float4 a20 = *(const float4*)&q2S[ty * 2][h4 * 4];
      const float4 a21 = *(const float4*)&q2S[ty * 2 + 1][h4 * 4];
#pragma unroll
      for (int jj = 0; jj < JPT; ++jj) {
        const float4 kk4 = *(const float4*)&kvS[tx + jj * 16][h4 * 4];
        sc[0][jj] = fmaf(aw0.x, kk4.x, fmaf(aw0.y, kk4.y,
                    fmaf(aw0.z, kk4.z, fmaf(aw0.w, kk4.w, sc[0][jj]))));
        sc[1][jj] = fmaf(aw1.x, kk4.x, fmaf(aw1.y, kk4.y,
                    fmaf(aw1.z, kk4.z, fmaf(aw1.w, kk4.w, sc[1][jj]))));
        const float4 w0 = *(const float4*)&bandS[ril[0][jj]][h4 * 4];
        sc[0][jj] = fmaf(a20.x, w0.x, fmaf(a20.y, w0.y,
                    fmaf(a20.z, w0.z, fmaf(a20.w, w0.w, sc[0][jj]))));
        const float4 w1 = *(const float4*)&bandS[ril[1][jj]][h4 * 4];
        sc[1][jj] = fmaf(a21.x, w1.x, fmaf(a21.y, w1.y,
                    fmaf(a21.z, w1.z, fmaf(a21.w, w1.w, sc[1][jj]))));
      }
    }
#pragma unroll
    for (int ii = 0; ii < 2; ++ii)
#pragma unroll
      for (int jj = 0; jj < JPT; ++jj) {
        const int i = ty * 2 + ii, j = tx + jj * 16;
        const int iq = idqS[i], ik = idkS[j];
        const int sel = (iq == ik) | (iq == 2) | (ik == 2);
        PS[i][j] = sc[ii][jj] + (sel ? tb1[i] : tb0[i]);
      }
    __syncthreads();
    {
      const int i = ip, g = tid & 7;
      float mx = -1e30f;
#pragma unroll
      for (int c = 0; c < CPL; ++c) mx = fmaxf(mx, PS[i][g * CPL + c]);
#pragma unroll
      for (int off = 1; off < 8; off <<= 1)
        mx = fmaxf(mx, __shfl_xor(mx, off, 64));
      const float mold = mrow[i];
      const float mnew = fmaxf(mold, mx);
      float sum = 0.f;
#pragma unroll
      for (int c = 0; c < CPL; ++c) {
        const float p = __expf(PS[i][g * CPL + c] - mnew);
        PS[i][g * CPL + c] = p;
        sum += p;
      }
#pragma unroll
      for (int off = 1; off < 8; off <<= 1) sum += __shfl_xor(sum, off, 64);
      if (g == 0) {
        const float al = __expf(mold - mnew);
        arow[i] = al;
        lrow[i] = lrow[i] * al + sum;
        mrow[i] = mnew;
      }
    }
    __syncthreads();
    {
      const float al = arow[ip];
#pragma unroll
      for (int x = 0; x < 8; ++x) o[x] *= al;
    }
    const float* vb = v + ((size_t)b * Lk + jt) * DMODEL + n * 64;
    for (int e = tid; e < TK * 64; e += 256) {
      const int j = e >> 6, h = e & 63;
      kvS[j][h] = vb[(size_t)j * DMODEL + h];
    }
    __syncthreads();
#pragma unroll 8
    for (int j = 0; j < TK; ++j) {
      const float p = PS[ip][j];
      const float4 v0 = *(const float4*)&kvS[j][hp];
      const float4 v1 = *(const float4*)&kvS[j][hp + 4];
      o[0] = fmaf(p, v0.x, o[0]); o[1] = fmaf(p, v0.y, o[1]);
      o[2] = fmaf(p, v0.z, o[2]); o[3] = fmaf(p, v0.w, o[3]);
      o[4] = fmaf(p, v1.x, o[4]); o[5] = fmaf(p, v1.y, o[5]);
      o[6] = fmaf(p, v1.z, o[6]); o[7] = fmaf(p, v1.w, o[7]);
    }
  }
  const float linv = 1.0f / lrow[ip];
  float* ob = vec + ((size_t)b * Lq + i0 + ip) * DMODEL + n * 64 + hp;
#pragma unroll
  for (int x = 0; x < 8; ++x) ob[x] = o[x] * linv;
}

// =====================================================================
// Host: 12 layers, processed l=11..0.
// l 0-3 : self  Lq=Lk=1024 sq=sk=1
// l 4   : up    Lq=1024 Lk=512 sq=1 sk=2 (sigma=-1); q_in = upsample of
//               BLOCK-ENTRY hidden (= layer-8 output), computed before l=7
// l 5-7 : self  Lq=Lk=512  sq=sk=2
// l 8   : up    Lq=512 Lk=256 sq=2 sk=4 (sigma=-1); q_in = upsample of
//               final_hidden, computed before l=11
// l 9-11: self  Lq=Lk=256  sq=sk=4
// =====================================================================
extern "C" void kernel_launch(void* const* d_in, const int* in_sizes, int n_in,
                              void* d_out, int out_size, void* d_ws,
                              size_t ws_size, hipStream_t stream)
{
  const float* final_hidden = (const float*)d_in[0];
  const int* ids = (const int*)d_in[5];
  const float* Wq = (const float*)d_in[6];
  const float* bq = (const float*)d_in[7];
  const float* Wk = (const float*)d_in[8];
  const float* bk = (const float*)d_in[9];
  const float* Wv = (const float*)d_in[10];
  const float* bvv = (const float*)d_in[11];
  const float* rw = (const float*)d_in[12];
  const float* rr = (const float*)d_in[13];
  const float* rs = (const float*)d_in[14];
  const float* rk = (const float*)d_in[15];
  const float* seg = (const float*)d_in[16];
  const float* Wp = (const float*)d_in[17];
  const float* bp = (const float*)d_in[18];
  const float* lng = (const float*)d_in[19];
  const float* lnb = (const float*)d_in[20];

  float* ws = (float*)d_ws;
  const size_t NB = (size_t)2 * 1024 * 1024;  // 2M floats per buffer
  float* hA    = ws;
  float* hB    = ws + NB;
  float* upB   = ws + 2 * NB;
  float* qB    = ws + 3 * NB;
  float* kB    = ws + 4 * NB;
  float* vB    = ws + 5 * NB;
  float* vecB  = ws + 6 * NB;
  float* wrelB = ws + 7 * NB;   // max 16*2047*64 floats
  float* trigB = ws + 8 * NB;   // max 1024*2047 floats

  const float* X = final_hidden;

  for (int l = 11; l >= 0; --l) {
    int Lq, Lk, sq, sk, sqp, skp, rmin, rstep, nrel, rbase;
    float sgn;
    if (l <= 3)      { Lq=1024; Lk=1024; sq=1; sk=1; sqp=1; skp=1; rmin=-1023; rstep=1; nrel=2047; rbase=1023; sgn= 1.f; }
    else if (l == 4) { Lq=1024; Lk= 512; sq=1; sk=2; sqp=1; skp=2; rmin=-1022; rstep=1; nrel=2046; rbase=1022; sgn=-1.f; }
    else if (l <= 7) { Lq= 512; Lk= 512; sq=2; sk=2; sqp=1; skp=1; rmin=-1022; rstep=2; nrel=1023; rbase= 511; sgn= 1.f; }
    else if (l == 8) { Lq= 512; Lk= 256; sq=2; sk=4; sqp=1; skp=2; rmin=-1020; rstep=2; nrel=1022; rbase= 510; sgn=-1.f; }
    else             { Lq= 256; Lk= 256; sq=4; sk=4; sqp=1; skp=1; rmin=-1020; rstep=4; nrel= 511; rbase= 255; sgn= 1.f; }

    // Block-entry upsample (reference computes `up` BEFORE the block's
    // self-layers run):
    if (l == 11) {  // from final_hidden (B,256)->(B,512), used at l=8
      const size_t total = (size_t)BATCH * 512 * DMODEL;
      upsample_k<<<dim3((unsigned)((total + 255) / 256)), 256, 0, stream>>>(
          X, upB, 256);
    } else if (l == 7) {  // from layer-8 output (B,512)->(B,1024), used at l=4
      const size_t total = (size_t)BATCH * 1024 * DMODEL;
      upsample_k<<<dim3((unsigned)((total + 255) / 256)), 256, 0, stream>>>(
          X, upB, 512);
    }
    const bool doUp = (l == 8) || (l == 4);
    const float* Xq = doUp ? upB : X;

    const int Mq = BATCH * Lq, Mk = BATCH * Lk;
    trig_fill<<<dim3((nrel + 255) / 256, DMODEL), 256, 0, stream>>>(
        trigB, nrel, rmin, rstep, sgn);
    gemm_k<3, true><<<dim3(DMODEL / 128, (nrel + 63) / 64), 256, 0, stream>>>(
        rk + (size_t)l * DMODEL * DMODEL, trigB, nullptr, nullptr, wrelB,
        DMODEL, nrel, DMODEL, nrel);
    gemm_k<1, false><<<dim3(Mq / 128, DMODEL / 64), 256, 0, stream>>>(
        Xq, Wq + (size_t)l * DMODEL * DMODEL, bq + l * DMODEL, nullptr, qB,
        Mq, DMODEL, DMODEL, 0);
    gemm_k<0, false><<<dim3(Mk / 128, DMODEL / 64), 256, 0, stream>>>(
        X, Wk + (size_t)l * DMODEL * DMODEL, bk + l * DMODEL, nullptr, kB,
        Mk, DMODEL, DMODEL, 0);
    gemm_k<0, false><<<dim3(Mk / 128, DMODEL / 64), 256, 0, stream>>>(
        X, Wv + (size_t)l * DMODEL * DMODEL, bvv + l * DMODEL, nullptr, vB,
        Mk, DMODEL, DMODEL, 0);
    dim3 ag(Lq / 32, NHEAD, BATCH);
    if (skp == 1)
      attn_k<64><<<ag, 256, 0, stream>>>(qB, kB, vB, wrelB,
          rw + l * NHEAD * 64, rr + l * NHEAD * 64, rs + l * NHEAD * 64,
          seg + l * 2 * NHEAD * 64, ids, vecB,
          Lq, Lk, sq, sk, sqp, skp, rbase, nrel);
    else
      attn_k<32><<<ag, 256, 0, stream>>>(qB, kB, vB, wrelB,
          rw + l * NHEAD * 64, rr + l * NHEAD * 64, rs + l * NHEAD * 64,
          seg + l * 2 * NHEAD * 64, ids, vecB,
          Lq, Lk, sq, sk, sqp, skp, rbase, nrel);
    // post projection + residual (reuse kB as temp)
    gemm_k<2, false><<<dim3(Mq / 128, DMODEL / 64), 256, 0, stream>>>(
        vecB, Wp + (size_t)l * DMODEL * DMODEL, bp + l * DMODEL, Xq, kB,
        Mq, DMODEL, DMODEL, 0);
    float* outBuf = (l == 0) ? (float*)d_out : ((X == hA) ? hB : hA);
    ln_k<<<dim3(Mq), 256, 0, stream>>>(
        kB, lng + l * DMODEL, lnb + l * DMODEL, outBuf);
    X = outBuf;
  }
  (void)in_sizes; (void)n_in; (void)out_size; (void)ws_size;
}

// Round 3
// 6914.021 us; speedup vs baseline: 1.9612x; 1.9612x over previous
//
#include <hip/hip_runtime.h>
#include <math.h>

#define NHEAD 16
#define DMODEL 1024
#define BATCH 2
#define QSCALE 0.125f

typedef __attribute__((ext_vector_type(8))) short bf16x8;
typedef __attribute__((ext_vector_type(4))) float f32x4;

__device__ inline unsigned short f2bf(float x) {
  unsigned int u = __float_as_uint(x);
  u += 0x7FFF + ((u >> 16) & 1);
  return (unsigned short)(u >> 16);
}
__device__ inline float bf2f(unsigned short h) {
  return __uint_as_float(((unsigned int)h) << 16);
}

// =====================================================================
// bf16 MFMA GEMM: C[M,N] = A @ B, A bf16 [M][K], Bt bf16 [Npad][K]
// (row n of Bt = column n of B). Tile 128x128, BK=64, 256 thr = 4 waves,
// each wave a 64x64 quadrant (4x4 frags of 16x16x32). Fragment-contiguous
// LDS: frag = 64 lanes x 16B; ds_read_b128 at lane*16 (conflict-free).
// MODE 0: +bias (fp32 out). MODE 1: (acc+bias)*QSCALE. MODE 2:
// acc+bias+bf2f(R[m][n]). MODE 3: wrel store C[head][r][h], m=head*64+h.
// =====================================================================
template<int MODE>
__global__ __launch_bounds__(256) void gemm_bf16(
    const unsigned short* __restrict__ A, const unsigned short* __restrict__ Bt,
    const float* __restrict__ bias, const unsigned short* __restrict__ R,
    float* __restrict__ C, int M, int N, int K, int nrel)
{
  __shared__ unsigned short smem[32 * 512];  // A frags 0..15, B frags 16..31
  const int tid = threadIdx.x;
  const int lane = tid & 63, w = tid >> 6;
  const int mw = w >> 1, nw = w & 1;
  const int bm = blockIdx.x * 128, bn = blockIdx.y * 128;
  const int lm = lane & 15, lq = lane >> 4;

  f32x4 acc[4][4];
#pragma unroll
  for (int i = 0; i < 4; ++i)
#pragma unroll
    for (int j = 0; j < 4; ++j) acc[i][j] = (f32x4){0.f, 0.f, 0.f, 0.f};

  for (int k0 = 0; k0 < K; k0 += 64) {
    // stage: wave w handles A frags f=w,w+4,w+8,w+12 and same B frag ids.
#pragma unroll
    for (int f = w; f < 16; f += 4) {
      const int kb = f >> 3, mb = f & 7;
      const int gr = bm + mb * 16 + lm;
      const int gc = k0 + kb * 32 + lq * 8;
      const uint4 va = *(const uint4*)(A + (size_t)gr * K + gc);
      *(uint4*)(&smem[f * 512 + lane * 8]) = va;
      const int nr = bn + mb * 16 + lm;  // same frag pattern for B
      const uint4 vb = *(const uint4*)(Bt + (size_t)nr * K + gc);
      *(uint4*)(&smem[(16 + f) * 512 + lane * 8]) = vb;
    }
    __syncthreads();
#pragma unroll
    for (int kb = 0; kb < 2; ++kb) {
      bf16x8 af[4], bf[4];
#pragma unroll
      for (int i = 0; i < 4; ++i)
        af[i] = *(const bf16x8*)(&smem[(kb * 8 + mw * 4 + i) * 512 + lane * 8]);
#pragma unroll
      for (int j = 0; j < 4; ++j)
        bf[j] = *(const bf16x8*)(&smem[(16 + kb * 8 + nw * 4 + j) * 512 + lane * 8]);
#pragma unroll
      for (int i = 0; i < 4; ++i)
#pragma unroll
        for (int j = 0; j < 4; ++j)
          acc[i][j] = __builtin_amdgcn_mfma_f32_16x16x32_bf16(
              af[i], bf[j], acc[i][j], 0, 0, 0);
    }
    __syncthreads();
  }
#pragma unroll
  for (int i = 0; i < 4; ++i) {
#pragma unroll
    for (int j = 0; j < 4; ++j) {
      const int col = bn + nw * 64 + j * 16 + lm;
      if (col >= N) continue;
#pragma unroll
      for (int r = 0; r < 4; ++r) {
        const int row = bm + mw * 64 + i * 16 + lq * 4 + r;
        float vv = acc[i][j][r];
        if (MODE == 0) vv += bias[col];
        else if (MODE == 1) vv = (vv + bias[col]) * QSCALE;
        else if (MODE == 2) vv = vv + bias[col] + bf2f(R[(size_t)row * N + col]);
        if (MODE == 3)
          C[(((size_t)(row >> 6)) * nrel + col) * 64 + (row & 63)] = vv;
        else
          C[(size_t)row * N + col] = vv;
      }
    }
  }
}

// =====================================================================
// transpose + fp32->bf16: in [1024][1024] fp32 -> out [1024][1024] bf16^T
// =====================================================================
__global__ __launch_bounds__(256) void tpose_k(
    const float* __restrict__ in, unsigned short* __restrict__ out)
{
  __shared__ float t[32][33];
  const int bi = blockIdx.x * 32, bj = blockIdx.y * 32;
  const int r = threadIdx.x >> 3, c4 = (threadIdx.x & 7) * 4;
  const float4 v = *(const float4*)(in + (size_t)(bi + r) * 1024 + bj + c4);
  t[r][c4] = v.x; t[r][c4 + 1] = v.y; t[r][c4 + 2] = v.z; t[r][c4 + 3] = v.w;
  __syncthreads();
  ushort4 o;
  o.x = f2bf(t[c4 + 0][r]); o.y = f2bf(t[c4 + 1][r]);
  o.z = f2bf(t[c4 + 2][r]); o.w = f2bf(t[c4 + 3][r]);
  *(ushort4*)(out + (size_t)(bj + r) * 1024 + bi + c4) = o;
}

// fp32 -> bf16 elementwise
__global__ void cvt_k(const float* __restrict__ in,
                      unsigned short* __restrict__ out, int n)
{
  const int i = blockIdx.x * 256 + threadIdx.x;
  if (i < n) out[i] = f2bf(in[i]);
}

// =====================================================================
// trig table (bf16, transposed): T[r][f] = sgn*sin(ang), T[r][f+512]=cos(ang)
// ang = (rmin + r*rstep)*invfreq(f). Rows filled to rPad (padded for tiles).
// =====================================================================
__global__ void trig_fill(unsigned short* __restrict__ T, int rPad, int rmin,
                          int rstep, float sgn)
{
  const int idx = blockIdx.x * 256 + threadIdx.x;
  if (idx >= rPad * 512) return;
  const int r = idx >> 9, f = idx & 511;
  const float invf = expf((float)f * -(9.210340371976184f / 512.0f));
  const float ang = (float)(rmin + r * rstep) * invf;
  float s, c;
  sincosf(ang, &s, &c);
  T[(size_t)r * 1024 + f] = f2bf(sgn * s);
  T[(size_t)r * 1024 + f + 512] = f2bf(c);
}

// =====================================================================
// upsample (bf16): out[b][2t]=h[b][t]; out[b][2t+1]=0.5*(h[t]+h[(t-1)%L])
// Runs at BLOCK ENTRY per the reference.
// =====================================================================
__global__ void upsample_k(const unsigned short* __restrict__ h,
                           unsigned short* __restrict__ out, int L)
{
  const size_t idx = (size_t)blockIdx.x * 256 + threadIdx.x;
  const size_t total = (size_t)BATCH * 2 * L * DMODEL;
  if (idx >= total) return;
  const int d = (int)(idx & 1023);
  const int t2 = (int)((idx >> 10) % (size_t)(2 * L));
  const int b = (int)((idx >> 10) / (size_t)(2 * L));
  const unsigned short* hb = h + (size_t)b * L * DMODEL;
  float val;
  if ((t2 & 1) == 0) {
    val = bf2f(hb[(size_t)(t2 >> 1) * DMODEL + d]);
  } else {
    const int t = (t2 - 1) >> 1;
    const int prev = (t == 0) ? (L - 1) : (t - 1);
    val = 0.5f * (bf2f(hb[(size_t)t * DMODEL + d]) +
                  bf2f(hb[(size_t)prev * DMODEL + d]));
  }
  out[idx] = f2bf(val);
}

// =====================================================================
// LayerNorm over D=1024; fp32 in; bf16 out (hidden) or fp32 out (d_out).
// =====================================================================
template<bool BF16OUT>
__global__ __launch_bounds__(256) void ln_k(
    const float* __restrict__ x, const float* __restrict__ g,
    const float* __restrict__ b, void* __restrict__ outv)
{
  const int row = blockIdx.x;
  const int tid = threadIdx.x;
  const float* xr = x + (size_t)row * DMODEL;
  const float4 xv = *(const float4*)(xr + tid * 4);
  __shared__ float red[4];
  float s = xv.x + xv.y + xv.z + xv.w;
#pragma unroll
  for (int off = 32; off > 0; off >>= 1) s += __shfl_down(s, off, 64);
  if ((tid & 63) == 0) red[tid >> 6] = s;
  __syncthreads();
  const float mean = (red[0] + red[1] + red[2] + red[3]) * (1.f / 1024.f);
  const float dx = xv.x - mean, dy = xv.y - mean;
  const float dz = xv.z - mean, dw = xv.w - mean;
  float vs = dx * dx + dy * dy + dz * dz + dw * dw;
  __syncthreads();
#pragma unroll
  for (int off = 32; off > 0; off >>= 1) vs += __shfl_down(vs, off, 64);
  if ((tid & 63) == 0) red[tid >> 6] = vs;
  __syncthreads();
  const float var = (red[0] + red[1] + red[2] + red[3]) * (1.f / 1024.f);
  const float rstd = rsqrtf(var + 1e-9f);
  const float4 gv = *(const float4*)(g + tid * 4);
  const float4 bv = *(const float4*)(b + tid * 4);
  const float ox = dx * rstd * gv.x + bv.x;
  const float oy = dy * rstd * gv.y + bv.y;
  const float oz = dz * rstd * gv.z + bv.z;
  const float ow = dw * rstd * gv.w + bv.w;
  if (BF16OUT) {
    ushort4 o = {f2bf(ox), f2bf(oy), f2bf(oz), f2bf(ow)};
    *(ushort4*)((unsigned short*)outv + (size_t)row * DMODEL + tid * 4) = o;
  } else {
    float4 o = {ox, oy, oz, ow};
    *(float4*)((float*)outv + (size_t)row * DMODEL + tid * 4) = o;
  }
}

// =====================================================================
// Flash attention (fp32), unchanged except vec output is bf16.
// =====================================================================
template<int TK>
__global__ __launch_bounds__(256) void attn_k(
    const float* __restrict__ q, const float* __restrict__ k,
    const float* __restrict__ v, const float* __restrict__ wrel,
    const float* __restrict__ rw, const float* __restrict__ rr,
    const float* __restrict__ rs, const float* __restrict__ seg,
    const int* __restrict__ ids, unsigned short* __restrict__ vec,
    int Lq, int Lk, int sq, int sk, int sqp, int skp, int rbase, int nrel)
{
  constexpr int JPT = TK / 16;
  constexpr int CPL = TK / 8;
  __shared__ float qwS[32][68];
  __shared__ float q2S[32][68];
  __shared__ float kvS[64][68];
  __shared__ float bandS[95][68];
  __shared__ float PS[32][65];
  __shared__ float mrow[32], lrow[32], arow[32], tb0[32], tb1[32];
  __shared__ int idqS[32], idkS[64];

  const int tid = threadIdx.x;
  const int b = blockIdx.z;
  const int n = blockIdx.y;
  const int i0 = blockIdx.x * 32;
  const float* qb = q + ((size_t)b * Lq + i0) * DMODEL + n * 64;

  for (int e = tid; e < 32 * 64; e += 256) {
    const int i = e >> 6, h = e & 63;
    const float qv = qb[(size_t)i * DMODEL + h];
    qwS[i][h] = qv + rw[n * 64 + h] * QSCALE;
    q2S[i][h] = qv + rr[n * 64 + h] * QSCALE;
  }
  if (tid < 64) {
    const int i = tid >> 1, s_ = tid & 1;
    float a = 0.f;
    for (int h = 0; h < 64; ++h)
      a += (qb[(size_t)i * DMODEL + h] + rs[n * 64 + h] * QSCALE) *
           seg[(s_ * NHEAD + n) * 64 + h];
    if (s_) tb1[i] = a; else tb0[i] = a;
  }
  if (tid < 32) {
    mrow[tid] = -1e30f;
    lrow[tid] = 0.f;
    idqS[tid] = ids[b * 1024 + sq * (i0 + tid)];
  }
  float o[8];
#pragma unroll
  for (int x = 0; x < 8; ++x) o[x] = 0.f;
  const int tx = tid & 15, ty = tid >> 4;
  const int ip = tid >> 3, hp = (tid & 7) * 8;
  const int W = sqp * 31 + skp * (TK - 1) + 1;

  for (int jt = 0; jt < Lk; jt += TK) {
    __syncthreads();
    const float* kb = k + ((size_t)b * Lk + jt) * DMODEL + n * 64;
    for (int e = tid; e < TK * 64; e += 256) {
      const int j = e >> 6, h = e & 63;
      kvS[j][h] = kb[(size_t)j * DMODEL + h];
    }
    if (tid < TK) idkS[tid] = ids[b * 1024 + sk * (jt + tid)];
    const int rlo = sqp * i0 - skp * (jt + TK - 1) + rbase;
    const float* wb = wrel + ((size_t)n * nrel + rlo) * 64;
    for (int e = tid; e < W * 64; e += 256) {
      const int r = e >> 6, h = e & 63;
      bandS[r][h] = wb[(size_t)r * 64 + h];
    }
    __syncthreads();

    float sc[2][JPT];
    int ril[2][JPT];
#pragma unroll
    for (int ii = 0; ii < 2; ++ii)
#pragma unroll
      for (int jj = 0; jj < JPT; ++jj) {
        sc[ii][jj] = 0.f;
        ril[ii][jj] = sqp * (i0 + ty * 2 + ii) - skp * (jt + tx + jj * 16)
                      + rbase - rlo;
      }
#pragma unroll 4
    for (int h4 = 0; h4 < 16; ++h4) {
      const float4 aw0 = *(const float4*)&qwS[ty * 2][h4 * 4];
      const float4 aw1 = *(const float4*)&qwS[ty * 2 + 1][h4 * 4];
      const float4 a20 = *(const float4*)&q2S[ty * 2][h4 * 4];
      const float4 a21 = *(const float4*)&q2S[ty * 2 + 1][h4 * 4];
#pragma unroll
      for (int jj = 0; jj < JPT; ++jj) {
        const float4 kk4 = *(const float4*)&kvS[tx + jj * 16][h4 * 4];
        sc[0][jj] = fmaf(aw0.x, kk4.x, fmaf(aw0.y, kk4.y,
                    fmaf(aw0.z, kk4.z, fmaf(aw0.w, kk4.w, sc[0][jj]))));
        sc[1][jj] = fmaf(aw1.x, kk4.x, fmaf(aw1.y, kk4.y,
                    fmaf(aw1.z, kk4.z, fmaf(aw1.w, kk4.w, sc[1][jj]))));
        const float4 w0 = *(const float4*)&bandS[ril[0][jj]][h4 * 4];
        sc[0][jj] = fmaf(a20.x, w0.x, fmaf(a20.y, w0.y,
                    fmaf(a20.z, w0.z, fmaf(a20.w, w0.w, sc[0][jj]))));
        const float4 w1 = *(const float4*)&bandS[ril[1][jj]][h4 * 4];
        sc[1][jj] = fmaf(a21.x, w1.x, fmaf(a21.y, w1.y,
                    fmaf(a21.z, w1.z, fmaf(a21.w, w1.w, sc[1][jj]))));
      }
    }
#pragma unroll
    for (int ii = 0; ii < 2; ++ii)
#pragma unroll
      for (int jj = 0; jj < JPT; ++jj) {
        const int i = ty * 2 + ii, j = tx + jj * 16;
        const int iq = idqS[i], ik = idkS[j];
        const int sel = (iq == ik) | (iq == 2) | (ik == 2);
        PS[i][j] = sc[ii][jj] + (sel ? tb1[i] : tb0[i]);
      }
    __syncthreads();
    {
      const int i = ip, g = tid & 7;
      float mx = -1e30f;
#pragma unroll
      for (int c = 0; c < CPL; ++c) mx = fmaxf(mx, PS[i][g * CPL + c]);
#pragma unroll
      for (int off = 1; off < 8; off <<= 1)
        mx = fmaxf(mx, __shfl_xor(mx, off, 64));
      const float mold = mrow[i];
      const float mnew = fmaxf(mold, mx);
      float sum = 0.f;
#pragma unroll
      for (int c = 0; c < CPL; ++c) {
        const float p = __expf(PS[i][g * CPL + c] - mnew);
        PS[i][g * CPL + c] = p;
        sum += p;
      }
#pragma unroll
      for (int off = 1; off < 8; off <<= 1) sum += __shfl_xor(sum, off, 64);
      if (g == 0) {
        const float al = __expf(mold - mnew);
        arow[i] = al;
        lrow[i] = lrow[i] * al + sum;
        mrow[i] = mnew;
      }
    }
    __syncthreads();
    {
      const float al = arow[ip];
#pragma unroll
      for (int x = 0; x < 8; ++x) o[x] *= al;
    }
    const float* vb = v + ((size_t)b * Lk + jt) * DMODEL + n * 64;
    for (int e = tid; e < TK * 64; e += 256) {
      const int j = e >> 6, h = e & 63;
      kvS[j][h] = vb[(size_t)j * DMODEL + h];
    }
    __syncthreads();
#pragma unroll 8
    for (int j = 0; j < TK; ++j) {
      const float p = PS[ip][j];
      const float4 v0 = *(const float4*)&kvS[j][hp];
      const float4 v1 = *(const float4*)&kvS[j][hp + 4];
      o[0] = fmaf(p, v0.x, o[0]); o[1] = fmaf(p, v0.y, o[1]);
      o[2] = fmaf(p, v0.z, o[2]); o[3] = fmaf(p, v0.w, o[3]);
      o[4] = fmaf(p, v1.x, o[4]); o[5] = fmaf(p, v1.y, o[5]);
      o[6] = fmaf(p, v1.z, o[6]); o[7] = fmaf(p, v1.w, o[7]);
    }
  }
  const float linv = 1.0f / lrow[ip];
  unsigned short* ob = vec + ((size_t)b * Lq + i0 + ip) * DMODEL + n * 64 + hp;
  ushort4 o0 = {f2bf(o[0] * linv), f2bf(o[1] * linv),
                f2bf(o[2] * linv), f2bf(o[3] * linv)};
  ushort4 o1 = {f2bf(o[4] * linv), f2bf(o[5] * linv),
                f2bf(o[6] * linv), f2bf(o[7] * linv)};
  *(ushort4*)(ob) = o0;
  *(ushort4*)(ob + 4) = o1;
}

// =====================================================================
// Host
// =====================================================================
extern "C" void kernel_launch(void* const* d_in, const int* in_sizes, int n_in,
                              void* d_out, int out_size, void* d_ws,
                              size_t ws_size, hipStream_t stream)
{
  const float* final_hidden = (const float*)d_in[0];
  const int* ids = (const int*)d_in[5];
  const float* Wq = (const float*)d_in[6];
  const float* bq = (const float*)d_in[7];
  const float* Wk = (const float*)d_in[8];
  const float* bk = (const float*)d_in[9];
  const float* Wv = (const float*)d_in[10];
  const float* bvv = (const float*)d_in[11];
  const float* rw = (const float*)d_in[12];
  const float* rr = (const float*)d_in[13];
  const float* rs = (const float*)d_in[14];
  const float* rk = (const float*)d_in[15];
  const float* seg = (const float*)d_in[16];
  const float* Wp = (const float*)d_in[17];
  const float* bp = (const float*)d_in[18];
  const float* lng = (const float*)d_in[19];
  const float* lnb = (const float*)d_in[20];

  unsigned char* w8 = (unsigned char*)d_ws;
  const size_t MB = 1024 * 1024;
  unsigned short* hA    = (unsigned short*)(w8 + 0 * MB);   // 4 MB bf16
  unsigned short* hB    = (unsigned short*)(w8 + 4 * MB);   // 4 MB
  unsigned short* upB   = (unsigned short*)(w8 + 8 * MB);   // 4 MB
  float*          qB    = (float*)(w8 + 12 * MB);           // 8 MB
  float*          kB    = (float*)(w8 + 20 * MB);           // 8 MB (+post temp)
  float*          vB    = (float*)(w8 + 28 * MB);           // 8 MB
  unsigned short* vecB  = (unsigned short*)(w8 + 36 * MB);  // 4 MB
  float*          wrelB = (float*)(w8 + 40 * MB);           // 8.4 MB -> 9
  unsigned short* trigB = (unsigned short*)(w8 + 49 * MB);  // 4 MB [2048][1024]
  unsigned short* wtq   = (unsigned short*)(w8 + 53 * MB);  // 2 MB each
  unsigned short* wtk   = (unsigned short*)(w8 + 55 * MB);
  unsigned short* wtv   = (unsigned short*)(w8 + 57 * MB);
  unsigned short* wtp   = (unsigned short*)(w8 + 59 * MB);
  unsigned short* rkT   = (unsigned short*)(w8 + 61 * MB);  // ends 63 MB

  // final_hidden -> bf16 into hA
  {
    const int n = BATCH * 256 * DMODEL;
    cvt_k<<<dim3((n + 255) / 256), 256, 0, stream>>>(final_hidden, hA, n);
  }
  const unsigned short* X = hA;

  const dim3 tg(32, 32);
  for (int l = 11; l >= 0; --l) {
    int Lq, Lk, sq, sk, sqp, skp, rmin, rstep, nrel, rbase;
    float sgn;
    if (l <= 3)      { Lq=1024; Lk=1024; sq=1; sk=1; sqp=1; skp=1; rmin=-1023; rstep=1; nrel=2047; rbase=1023; sgn= 1.f; }
    else if (l == 4) { Lq=1024; Lk= 512; sq=1; sk=2; sqp=1; skp=2; rmin=-1022; rstep=1; nrel=2046; rbase=1022; sgn=-1.f; }
    else if (l <= 7) { Lq= 512; Lk= 512; sq=2; sk=2; sqp=1; skp=1; rmin=-1022; rstep=2; nrel=1023; rbase= 511; sgn= 1.f; }
    else if (l == 8) { Lq= 512; Lk= 256; sq=2; sk=4; sqp=1; skp=2; rmin=-1020; rstep=2; nrel=1022; rbase= 510; sgn=-1.f; }
    else             { Lq= 256; Lk= 256; sq=4; sk=4; sqp=1; skp=1; rmin=-1020; rstep=4; nrel= 511; rbase= 255; sgn= 1.f; }

    // block-entry upsample (reference order)
    if (l == 11) {
      const size_t total = (size_t)BATCH * 512 * DMODEL;
      upsample_k<<<dim3((unsigned)((total + 255) / 256)), 256, 0, stream>>>(
          X, upB, 256);
    } else if (l == 7) {
      const size_t total = (size_t)BATCH * 1024 * DMODEL;
      upsample_k<<<dim3((unsigned)((total + 255) / 256)), 256, 0, stream>>>(
          X, upB, 512);
    }
    const bool doUp = (l == 8) || (l == 4);
    const unsigned short* Xq = doUp ? upB : X;
    const int Mq = BATCH * Lq, Mk = BATCH * Lk;
    const int rPad = ((nrel + 127) / 128) * 128;

    // weight transposes (fp32 -> bf16 [n][k])
    tpose_k<<<tg, 256, 0, stream>>>(Wq + (size_t)l * DMODEL * DMODEL, wtq);
    tpose_k<<<tg, 256, 0, stream>>>(Wk + (size_t)l * DMODEL * DMODEL, wtk);
    tpose_k<<<tg, 256, 0, stream>>>(Wv + (size_t)l * DMODEL * DMODEL, wtv);
    tpose_k<<<tg, 256, 0, stream>>>(Wp + (size_t)l * DMODEL * DMODEL, wtp);
    tpose_k<<<tg, 256, 0, stream>>>(rk + (size_t)l * DMODEL * DMODEL, rkT);

    trig_fill<<<dim3((rPad * 512 + 255) / 256), 256, 0, stream>>>(
        trigB, rPad, rmin, rstep, sgn);
    // Wrel[head][r][h] = sum_d rkT[head*64+h][d] * trig[r][d]
    gemm_bf16<3><<<dim3(DMODEL / 128, rPad / 128), 256, 0, stream>>>(
        rkT, trigB, nullptr, nullptr, wrelB, DMODEL, nrel, DMODEL, nrel);
    gemm_bf16<1><<<dim3(Mq / 128, 8), 256, 0, stream>>>(
        Xq, wtq, bq + l * DMODEL, nullptr, qB, Mq, DMODEL, DMODEL, 0);
    gemm_bf16<0><<<dim3(Mk / 128, 8), 256, 0, stream>>>(
        X, wtk, bk + l * DMODEL, nullptr, kB, Mk, DMODEL, DMODEL, 0);
    gemm_bf16<0><<<dim3(Mk / 128, 8), 256, 0, stream>>>(
        X, wtv, bvv + l * DMODEL, nullptr, vB, Mk, DMODEL, DMODEL, 0);

    dim3 ag(Lq / 32, NHEAD, BATCH);
    if (skp == 1)
      attn_k<64><<<ag, 256, 0, stream>>>(qB, kB, vB, wrelB,
          rw + l * NHEAD * 64, rr + l * NHEAD * 64, rs + l * NHEAD * 64,
          seg + l * 2 * NHEAD * 64, ids, vecB,
          Lq, Lk, sq, sk, sqp, skp, rbase, nrel);
    else
      attn_k<32><<<ag, 256, 0, stream>>>(qB, kB, vB, wrelB,
          rw + l * NHEAD * 64, rr + l * NHEAD * 64, rs + l * NHEAD * 64,
          seg + l * 2 * NHEAD * 64, ids, vecB,
          Lq, Lk, sq, sk, sqp, skp, rbase, nrel);

    // post projection + residual (kB reused as fp32 temp)
    gemm_bf16<2><<<dim3(Mq / 128, 8), 256, 0, stream>>>(
        vecB, wtp, bp + l * DMODEL, Xq, kB, Mq, DMODEL, DMODEL, 0);
    if (l == 0) {
      ln_k<false><<<dim3(Mq), 256, 0, stream>>>(
          kB, lng + l * DMODEL, lnb + l * DMODEL, d_out);
    } else {
      unsigned short* outBuf = (X == hA) ? hB : hA;
      ln_k<true><<<dim3(Mq), 256, 0, stream>>>(
          kB, lng + l * DMODEL, lnb + l * DMODEL, outBuf);
      X = outBuf;
    }
  }
  (void)in_sizes; (void)n_in; (void)out_size; (void)ws_size;
}